// Round 1
// baseline (1750.801 us; speedup 1.0000x reference)
//
#include <hip/hip_runtime.h>
#include <math.h>

#define B_   4
#define S_   512
#define DH   1600
#define NH   50
#define PH   32
#define NREL 100

__device__ __forceinline__ float gelu_f(float x) {
    // exact gelu: 0.5 x (1 + erf(x/sqrt(2)))
    return 0.5f * x * (1.0f + erff(x * 0.70710678118654752f));
}

// ---------------------------------------------------------------------------
// GEMM: C = A @ Bm + bias, optional exact GELU epilogue.
// A:[M,K] B:[K,N] C:[M,N], all fp32 row-major. M=2048, N=K=1600.
// 64x64 tile, BK=16, 256 threads, 4x4 per thread. No bounds guards needed:
// M%64==0, N%64==0, K%16==0.
// blockIdx.z selects among 3 (B,bias,C) triples so QKV runs as one launch.
// ---------------------------------------------------------------------------
template<bool GELU>
__global__ __launch_bounds__(256)
void gemm_k(const float* __restrict__ A,
            const float* __restrict__ B0, const float* __restrict__ B1, const float* __restrict__ B2,
            const float* __restrict__ bi0, const float* __restrict__ bi1, const float* __restrict__ bi2,
            float* __restrict__ C0, float* __restrict__ C1, float* __restrict__ C2,
            int M, int N, int K)
{
    const int z = blockIdx.z;
    const float* Bm = (z == 0) ? B0 : (z == 1) ? B1 : B2;
    const float* bi = (z == 0) ? bi0 : (z == 1) ? bi1 : B2 == B1 ? bi1 : bi2;
    bi = (z == 0) ? bi0 : (z == 1) ? bi1 : bi2;
    float* C = (z == 0) ? C0 : (z == 1) ? C1 : C2;

    __shared__ float As[16][68];   // stored transposed: As[k][m], +4 pad
    __shared__ float Bs[16][68];   // Bs[k][n], +4 pad

    const int tid = threadIdx.x;
    const int tx = tid & 15, ty = tid >> 4;
    const int bm = blockIdx.y * 64, bn = blockIdx.x * 64;

    // staging indices
    const int lr = tid >> 2;          // 0..63 : A tile row
    const int lc = (tid & 3) * 4;     // 0,4,8,12 : A tile k-offset
    const int brow = tid >> 4;        // 0..15 : B tile k-row
    const int bcol = (tid & 15) * 4;  // 0..60 : B tile col

    float4 acc[4] = {};               // acc[i] = row ty*4+i, cols tx*4..tx*4+3

    for (int k0 = 0; k0 < K; k0 += 16) {
        float4 av = *(const float4*)&A [(size_t)(bm + lr) * K + k0 + lc];
        float4 bv = *(const float4*)&Bm[(size_t)(k0 + brow) * N + bn + bcol];
        __syncthreads();   // previous iteration's LDS reads complete
        As[lc + 0][lr] = av.x;
        As[lc + 1][lr] = av.y;
        As[lc + 2][lr] = av.z;
        As[lc + 3][lr] = av.w;
        *(float4*)&Bs[brow][bcol] = bv;
        __syncthreads();
        #pragma unroll
        for (int kk = 0; kk < 16; kk++) {
            float4 a = *(const float4*)&As[kk][ty * 4];
            float4 b = *(const float4*)&Bs[kk][tx * 4];
            float ar[4] = {a.x, a.y, a.z, a.w};
            #pragma unroll
            for (int i = 0; i < 4; i++) {
                acc[i].x += ar[i] * b.x;
                acc[i].y += ar[i] * b.y;
                acc[i].z += ar[i] * b.z;
                acc[i].w += ar[i] * b.w;
            }
        }
    }

    float4 bvv = *(const float4*)&bi[bn + tx * 4];
    #pragma unroll
    for (int i = 0; i < 4; i++) {
        int row = bm + ty * 4 + i;
        float4 r = acc[i];
        r.x += bvv.x; r.y += bvv.y; r.z += bvv.z; r.w += bvv.w;
        if (GELU) {
            r.x = gelu_f(r.x); r.y = gelu_f(r.y); r.z = gelu_f(r.z); r.w = gelu_f(r.w);
        }
        *(float4*)&C[(size_t)row * N + bn + tx * 4] = r;
    }
}

// ---------------------------------------------------------------------------
// Relation-aware attention, fp32, wave-per-query-row.
//   scores[q,k] = (q.k + qrel[q, rm[q,k]]) / sqrt(PH)
//   qrel[q,r]   = q . rel_k_emb[r]
//   ctx[q,d]    = sum_k p[q,k] * (v[k,d] + rel_v_emb[rm[q,k], d])
// Block = 256 threads = 4 waves = 4 consecutive query rows of one (b,h).
// k/v staged in LDS in 128-row chunks; scores/probs live in 8 regs/lane.
// CTX may alias Q: each block writes exactly the (rows, head-slice) only it
// reads, after reading them.
// ---------------------------------------------------------------------------
__global__ __launch_bounds__(256)
void attn_k(const float* __restrict__ Q, const float* __restrict__ Kt,
            const float* __restrict__ V,
            const float* __restrict__ relk, const float* __restrict__ relv,
            const int* __restrict__ RM, float* __restrict__ CTX)
{
    __shared__ float relbuf[NREL * 36];   // rel_k (stride 33) then rel_v (stride 36)
    __shared__ float kvbuf[128 * 36];     // k/v chunk, row stride 36 (16B-aligned rows)
    __shared__ float qrel_s[4][NREL];
    __shared__ float qrow_s[4][PH];
    __shared__ float p_row[4 * S_];
    __shared__ int   rm_row[4 * S_];

    const int tid = threadIdx.x;
    const int w = tid >> 6, lane = tid & 63;
    const int b = blockIdx.z, h = blockIdx.y, q0 = blockIdx.x * 4;

    // ---- P0: stage q rows + rel_k_emb (stride 33 -> conflict-free column reads)
    if (tid < 128) {
        int r = tid >> 5, d = tid & 31;
        qrow_s[r][d] = Q[(size_t)(b * S_ + q0 + r) * DH + h * PH + d];
    }
    for (int i = tid; i < NREL * PH; i += 256)
        relbuf[(i >> 5) * 33 + (i & 31)] = relk[i];
    __syncthreads();

    float qreg[PH];
    #pragma unroll
    for (int d = 0; d < PH; d++) qreg[d] = qrow_s[w][d];

    // ---- P1: qrel[r] = q . rel_k_emb[r]
    for (int r = lane; r < NREL; r += 64) {
        float s = 0.f;
        #pragma unroll
        for (int d = 0; d < PH; d++) s += qreg[d] * relbuf[r * 33 + d];
        qrel_s[w][r] = s;
    }

    const int* rmrow = &RM[(size_t)(b * S_ + q0 + w) * S_];
    float sc[8];

    // ---- P2: scores over 4 chunks of 128 keys
    for (int c = 0; c < 4; c++) {
        __syncthreads();   // all waves done reading previous chunk
        #pragma unroll
        for (int u = 0; u < 4; u++) {
            int idx = tid + u * 256;      // float4 index 0..1023
            int j = idx >> 3, g = idx & 7;
            float4 kv = *(const float4*)&Kt[(size_t)(b * S_ + c * 128 + j) * DH + h * PH + g * 4];
            *(float4*)&kvbuf[j * 36 + g * 4] = kv;
        }
        __syncthreads();
        #pragma unroll
        for (int sub = 0; sub < 2; sub++) {
            int jj = sub * 64 + lane;
            int jg = c * 128 + jj;
            int rm = rmrow[jg];
            float s = 0.f;
            #pragma unroll
            for (int g = 0; g < 8; g++) {
                float4 kv = *(const float4*)&kvbuf[jj * 36 + g * 4];
                s += qreg[g * 4 + 0] * kv.x + qreg[g * 4 + 1] * kv.y
                   + qreg[g * 4 + 2] * kv.z + qreg[g * 4 + 3] * kv.w;
            }
            s += qrel_s[w][rm];
            sc[c * 2 + sub] = s;
            rm_row[w * S_ + jg] = rm;
        }
    }

    // ---- P3: softmax over the wave's 512 logits (8 per lane)
    const float scale = 0.17677669529663689f;   // 1/sqrt(32)
    float m = -1e30f;
    #pragma unroll
    for (int i = 0; i < 8; i++) { sc[i] *= scale; m = fmaxf(m, sc[i]); }
    #pragma unroll
    for (int off = 32; off > 0; off >>= 1) m = fmaxf(m, __shfl_xor(m, off));
    float tsum = 0.f;
    #pragma unroll
    for (int i = 0; i < 8; i++) { sc[i] = __expf(sc[i] - m); tsum += sc[i]; }
    #pragma unroll
    for (int off = 32; off > 0; off >>= 1) tsum += __shfl_xor(tsum, off);
    float inv = 1.0f / tsum;
    #pragma unroll
    for (int i = 0; i < 8; i++) {
        int jg = (i >> 1) * 128 + (i & 1) * 64 + lane;
        p_row[w * S_ + jg] = sc[i] * inv;
    }

    // ---- P4 prelude: rel_v_emb with stride 36 (aligned float4 gathers).
    // Safe: any wave here has passed P2's barriers => all waves finished P1.
    for (int i = tid; i < NREL * PH; i += 256)
        relbuf[(i >> 5) * 36 + (i & 31)] = relv[i];

    // ---- P4: ctx = sum_k p * (v + rel_v[rm])
    const int jsub = lane >> 3, dg = lane & 7, d0 = dg * 4;
    float4 acc = {0.f, 0.f, 0.f, 0.f};
    for (int c = 0; c < 4; c++) {
        __syncthreads();   // all waves done reading previous chunk
        #pragma unroll
        for (int u = 0; u < 4; u++) {
            int idx = tid + u * 256;
            int j = idx >> 3, g = idx & 7;
            float4 vv = *(const float4*)&V[(size_t)(b * S_ + c * 128 + j) * DH + h * PH + g * 4];
            *(float4*)&kvbuf[j * 36 + g * 4] = vv;
        }
        __syncthreads();
        #pragma unroll
        for (int t = 0; t < 16; t++) {
            int jj = jsub * 16 + t;
            int jg = c * 128 + jj;
            float p  = p_row[w * S_ + jg];
            int   rm = rm_row[w * S_ + jg];
            float4 vv = *(const float4*)&kvbuf[jj * 36 + d0];
            float4 rv = *(const float4*)&relbuf[rm * 36 + d0];
            acc.x += p * (vv.x + rv.x);
            acc.y += p * (vv.y + rv.y);
            acc.z += p * (vv.z + rv.z);
            acc.w += p * (vv.w + rv.w);
        }
    }

    // reduce partial ctx across the 8 jsub groups (lanes differing in bits 3..5)
    #pragma unroll
    for (int off = 8; off < 64; off <<= 1) {
        acc.x += __shfl_xor(acc.x, off);
        acc.y += __shfl_xor(acc.y, off);
        acc.z += __shfl_xor(acc.z, off);
        acc.w += __shfl_xor(acc.w, off);
    }
    if (jsub == 0) {
        *(float4*)&CTX[(size_t)(b * S_ + q0 + w) * DH + h * PH + d0] = acc;
    }
}

// ---------------------------------------------------------------------------
extern "C" void kernel_launch(void* const* d_in, const int* in_sizes, int n_in,
                              void* d_out, int out_size, void* d_ws, size_t ws_size,
                              hipStream_t stream)
{
    const float* hidden = (const float*)d_in[0];
    const float* Wq = (const float*)d_in[1];  const float* bq = (const float*)d_in[2];
    const float* Wk = (const float*)d_in[3];  const float* bk = (const float*)d_in[4];
    const float* Wv = (const float*)d_in[5];  const float* bv = (const float*)d_in[6];
    const float* Wo = (const float*)d_in[7];  const float* bo = (const float*)d_in[8];
    const float* relk = (const float*)d_in[9];
    const float* relv = (const float*)d_in[10];
    const float* W1 = (const float*)d_in[11]; const float* b1 = (const float*)d_in[12];
    const float* W2 = (const float*)d_in[13]; const float* b2 = (const float*)d_in[14];
    const int*   RM = (const int*)d_in[15];
    float* out = (float*)d_out;

    const int M = B_ * S_;                 // 2048
    const size_t SZ = (size_t)M * DH;      // 3,276,800 floats = 13.1 MB

    float* qb = (float*)d_ws;              // q, later ctx, later dead
    float* kb = qb + SZ;                   // k, later attn_out
    float* vb = kb + SZ;                   // v, later ffn hidden
    // total ws use: 3 * 13.1 MB = 39.3 MB

    // QKV: one launch, blockIdx.z picks the matrix
    dim3 gqkv(DH / 64, M / 64, 3);         // 25 x 32 x 3 = 2400 blocks
    gemm_k<false><<<gqkv, 256, 0, stream>>>(hidden, Wq, Wk, Wv, bq, bk, bv,
                                            qb, kb, vb, M, DH, DH);

    // attention (ctx written into qb, aliasing q — safe, see kernel comment)
    dim3 gattn(S_ / 4, NH, B_);            // 128 x 50 x 4
    attn_k<<<gattn, 256, 0, stream>>>(qb, kb, vb, relk, relv, RM, qb);

    dim3 g1(DH / 64, M / 64, 1);           // 25 x 32
    // attn_out = ctx @ Wo + bo   (into kb)
    gemm_k<false><<<g1, 256, 0, stream>>>(qb, Wo, Wo, Wo, bo, bo, bo,
                                          kb, kb, kb, M, DH, DH);
    // h = gelu(attn_out @ W1 + b1)   (into vb)
    gemm_k<true><<<g1, 256, 0, stream>>>(kb, W1, W1, W1, b1, b1, b1,
                                         vb, vb, vb, M, DH, DH);
    // out = h @ W2 + b2
    gemm_k<false><<<g1, 256, 0, stream>>>(vb, W2, W2, W2, b2, b2, b2,
                                          out, out, out, M, DH, DH);
}

// Round 2
// 1024.452 us; speedup vs baseline: 1.7090x; 1.7090x over previous
//
#include <hip/hip_runtime.h>
#include <math.h>

#define B_   4
#define S_   512
#define DH   1600
#define NH   50
#define PH   32
#define NREL 100
#define MROWS (B_ * S_)          // 2048

typedef __bf16 bf16x8 __attribute__((ext_vector_type(8)));
typedef float  floatx4 __attribute__((ext_vector_type(4)));

__device__ __forceinline__ float gelu_f(float x) {
    return 0.5f * x * (1.0f + erff(x * 0.70710678118654752f));
}

__device__ __forceinline__ unsigned short f2bf(float f) {
    unsigned int u = __float_as_uint(f);
    u += 0x7fffu + ((u >> 16) & 1u);   // RNE
    return (unsigned short)(u >> 16);
}

// ---------------------------------------------------------------------------
// fcast: flat fp32 -> bf16 (float4 -> ushort4), n must be /4
// ---------------------------------------------------------------------------
__global__ __launch_bounds__(256)
void fcast_k(const float* __restrict__ in, unsigned short* __restrict__ out, int n4)
{
    int i = blockIdx.x * 256 + threadIdx.x;
    if (i < n4) {
        float4 v = *(const float4*)&in[i * 4];
        ushort4 o = { f2bf(v.x), f2bf(v.y), f2bf(v.z), f2bf(v.w) };
        *(ushort4*)&out[i * 4] = o;
    }
}

// ---------------------------------------------------------------------------
// wcast: W[K=1600][N=1600] fp32 -> Wt[N][K] bf16, 6 weights via blockIdx.z.
// 32x32 LDS tile transpose, conflict-free (stride 33).
// ---------------------------------------------------------------------------
__global__ __launch_bounds__(256)
void wcast_k(const float* __restrict__ W0, const float* __restrict__ W1,
             const float* __restrict__ W2, const float* __restrict__ W3,
             const float* __restrict__ W4, const float* __restrict__ W5,
             unsigned short* __restrict__ T)
{
    const int z = blockIdx.z;
    const float* W = (z==0)?W0:(z==1)?W1:(z==2)?W2:(z==3)?W3:(z==4)?W4:W5;
    unsigned short* out = T + (size_t)z * DH * DH;

    __shared__ float tile[32][33];
    const int t = threadIdx.x;
    const int n0 = blockIdx.x * 32, k0 = blockIdx.y * 32;
    const int r = t >> 3, c4 = (t & 7) * 4;

    float4 v = *(const float4*)&W[(size_t)(k0 + r) * DH + n0 + c4];
    tile[r][c4 + 0] = v.x; tile[r][c4 + 1] = v.y;
    tile[r][c4 + 2] = v.z; tile[r][c4 + 3] = v.w;
    __syncthreads();

    // write Wt[n][k] = W[k][n]
    ushort4 o = { f2bf(tile[c4 + 0][r]), f2bf(tile[c4 + 1][r]),
                  f2bf(tile[c4 + 2][r]), f2bf(tile[c4 + 3][r]) };
    *(ushort4*)&out[(size_t)(n0 + r) * DH + k0 + c4] = o;
}

// ---------------------------------------------------------------------------
// bf16 MFMA GEMM: C = A @ Wt^T + bias  (Wt is [N][K] bf16, i.e. B transposed)
// A:[M=2048][K=1600] bf16.  BM=128, BN=64, BK=32, 256 thr = 4 waves,
// wave tile 64x32 = 4x2 of 16x16 mfma (K=32 each).  fp32 accum.
// N%64==0, M%128==0, K%32==0 -> no guards.
// blockIdx.z picks among 3 (Wt,bias,C) for the fused QKV launch.
// LDS rows stride 40 bf16 (80 B): frag ds_read_b128 conflict-free per
// 8-lane phase (20m+4g mod 32 covers all 8 quads).
// ---------------------------------------------------------------------------
#define BM 128
#define BN 64
#define BK 32
#define LDA 40

template<bool GELU, bool WF32, bool WBF16>
__global__ __launch_bounds__(256)
void gemm_bf16_k(const unsigned short* __restrict__ Ab,
                 const unsigned short* __restrict__ Bt0,
                 const unsigned short* __restrict__ Bt1,
                 const unsigned short* __restrict__ Bt2,
                 const float* __restrict__ bi0, const float* __restrict__ bi1,
                 const float* __restrict__ bi2,
                 float* __restrict__ Cf0, float* __restrict__ Cf1, float* __restrict__ Cf2,
                 unsigned short* __restrict__ Cb0, unsigned short* __restrict__ Cb1,
                 unsigned short* __restrict__ Cb2)
{
    const int z = blockIdx.z;
    const unsigned short* Bt = (z==0)?Bt0:(z==1)?Bt1:Bt2;
    const float* bi = (z==0)?bi0:(z==1)?bi1:bi2;
    float* Cf = (z==0)?Cf0:(z==1)?Cf1:Cf2;
    unsigned short* Cb = (z==0)?Cb0:(z==1)?Cb1:Cb2;

    __shared__ unsigned short As[BM * LDA];   // 10240 B
    __shared__ unsigned short Bs[BN * LDA];   //  5120 B

    const int tid = threadIdx.x;
    const int lane = tid & 63, w = tid >> 6;
    const int bm = blockIdx.y * BM, bn = blockIdx.x * BN;
    const int wm = (w >> 1) * 64, wn = (w & 1) * 32;

    // staging addrs: A = 512 chunks of 16B (2/thread), B = 256 chunks (1/thread)
    const int ac0 = tid, ac1 = tid + 256;
    const size_t aoff0 = (size_t)(bm + (ac0 >> 2)) * DH + (ac0 & 3) * 8;
    const size_t aoff1 = (size_t)(bm + (ac1 >> 2)) * DH + (ac1 & 3) * 8;
    const size_t boff  = (size_t)(bn + (tid >> 2)) * DH + (tid & 3) * 8;
    const int al0 = (ac0 >> 2) * LDA + (ac0 & 3) * 8;
    const int al1 = (ac1 >> 2) * LDA + (ac1 & 3) * 8;
    const int bl  = (tid >> 2) * LDA + (tid & 3) * 8;

    const int fl_m = lane & 15, fl_g = (lane >> 4) * 8;

    floatx4 acc[4][2] = {};

    for (int k0 = 0; k0 < DH; k0 += BK) {
        uint4 av0 = *(const uint4*)&Ab[aoff0 + k0];
        uint4 av1 = *(const uint4*)&Ab[aoff1 + k0];
        uint4 bv  = *(const uint4*)&Bt[boff + k0];
        __syncthreads();                    // prior frag reads done
        *(uint4*)&As[al0] = av0;
        *(uint4*)&As[al1] = av1;
        *(uint4*)&Bs[bl]  = bv;
        __syncthreads();

        bf16x8 af[4], bf[2];
        #pragma unroll
        for (int mt = 0; mt < 4; mt++)
            af[mt] = *(const bf16x8*)&As[(wm + mt * 16 + fl_m) * LDA + fl_g];
        #pragma unroll
        for (int nt = 0; nt < 2; nt++)
            bf[nt] = *(const bf16x8*)&Bs[(wn + nt * 16 + fl_m) * LDA + fl_g];

        #pragma unroll
        for (int mt = 0; mt < 4; mt++)
            #pragma unroll
            for (int nt = 0; nt < 2; nt++)
                acc[mt][nt] = __builtin_amdgcn_mfma_f32_16x16x32_bf16(
                    af[mt], bf[nt], acc[mt][nt], 0, 0, 0);
    }

    const int row_q = (lane >> 4) * 4;
    #pragma unroll
    for (int mt = 0; mt < 4; mt++) {
        #pragma unroll
        for (int nt = 0; nt < 2; nt++) {
            const int col = bn + wn + nt * 16 + fl_m;
            const float bias = bi[col];
            #pragma unroll
            for (int r = 0; r < 4; r++) {
                const int row = bm + wm + mt * 16 + row_q + r;
                float v = acc[mt][nt][r] + bias;
                if (GELU) v = gelu_f(v);
                if (WF32)  Cf[(size_t)row * DH + col] = v;
                if (WBF16) Cb[(size_t)row * DH + col] = f2bf(v);
            }
        }
    }
}

// ---------------------------------------------------------------------------
// Relation-aware attention, fp32 (unchanged from R1 — verified).
// ---------------------------------------------------------------------------
__global__ __launch_bounds__(256)
void attn_k(const float* __restrict__ Q, const float* __restrict__ Kt,
            const float* __restrict__ V,
            const float* __restrict__ relk, const float* __restrict__ relv,
            const int* __restrict__ RM, float* __restrict__ CTX)
{
    __shared__ float relbuf[NREL * 36];
    __shared__ float kvbuf[128 * 36];
    __shared__ float qrel_s[4][NREL];
    __shared__ float qrow_s[4][PH];
    __shared__ float p_row[4 * S_];
    __shared__ int   rm_row[4 * S_];

    const int tid = threadIdx.x;
    const int w = tid >> 6, lane = tid & 63;
    const int b = blockIdx.z, h = blockIdx.y, q0 = blockIdx.x * 4;

    if (tid < 128) {
        int r = tid >> 5, d = tid & 31;
        qrow_s[r][d] = Q[(size_t)(b * S_ + q0 + r) * DH + h * PH + d];
    }
    for (int i = tid; i < NREL * PH; i += 256)
        relbuf[(i >> 5) * 33 + (i & 31)] = relk[i];
    __syncthreads();

    float qreg[PH];
    #pragma unroll
    for (int d = 0; d < PH; d++) qreg[d] = qrow_s[w][d];

    for (int r = lane; r < NREL; r += 64) {
        float s = 0.f;
        #pragma unroll
        for (int d = 0; d < PH; d++) s += qreg[d] * relbuf[r * 33 + d];
        qrel_s[w][r] = s;
    }

    const int* rmrow = &RM[(size_t)(b * S_ + q0 + w) * S_];
    float sc[8];

    for (int c = 0; c < 4; c++) {
        __syncthreads();
        #pragma unroll
        for (int u = 0; u < 4; u++) {
            int idx = tid + u * 256;
            int j = idx >> 3, g = idx & 7;
            float4 kv = *(const float4*)&Kt[(size_t)(b * S_ + c * 128 + j) * DH + h * PH + g * 4];
            *(float4*)&kvbuf[j * 36 + g * 4] = kv;
        }
        __syncthreads();
        #pragma unroll
        for (int sub = 0; sub < 2; sub++) {
            int jj = sub * 64 + lane;
            int jg = c * 128 + jj;
            int rm = rmrow[jg];
            float s = 0.f;
            #pragma unroll
            for (int g = 0; g < 8; g++) {
                float4 kv = *(const float4*)&kvbuf[jj * 36 + g * 4];
                s += qreg[g * 4 + 0] * kv.x + qreg[g * 4 + 1] * kv.y
                   + qreg[g * 4 + 2] * kv.z + qreg[g * 4 + 3] * kv.w;
            }
            s += qrel_s[w][rm];
            sc[c * 2 + sub] = s;
            rm_row[w * S_ + jg] = rm;
        }
    }

    const float scale = 0.17677669529663689f;
    float m = -1e30f;
    #pragma unroll
    for (int i = 0; i < 8; i++) { sc[i] *= scale; m = fmaxf(m, sc[i]); }
    #pragma unroll
    for (int off = 32; off > 0; off >>= 1) m = fmaxf(m, __shfl_xor(m, off));
    float tsum = 0.f;
    #pragma unroll
    for (int i = 0; i < 8; i++) { sc[i] = __expf(sc[i] - m); tsum += sc[i]; }
    #pragma unroll
    for (int off = 32; off > 0; off >>= 1) tsum += __shfl_xor(tsum, off);
    float inv = 1.0f / tsum;
    #pragma unroll
    for (int i = 0; i < 8; i++) {
        int jg = (i >> 1) * 128 + (i & 1) * 64 + lane;
        p_row[w * S_ + jg] = sc[i] * inv;
    }

    for (int i = tid; i < NREL * PH; i += 256)
        relbuf[(i >> 5) * 36 + (i & 31)] = relv[i];

    const int jsub = lane >> 3, dg = lane & 7, d0 = dg * 4;
    float4 acc = {0.f, 0.f, 0.f, 0.f};
    for (int c = 0; c < 4; c++) {
        __syncthreads();
        #pragma unroll
        for (int u = 0; u < 4; u++) {
            int idx = tid + u * 256;
            int j = idx >> 3, g = idx & 7;
            float4 vv = *(const float4*)&V[(size_t)(b * S_ + c * 128 + j) * DH + h * PH + g * 4];
            *(float4*)&kvbuf[j * 36 + g * 4] = vv;
        }
        __syncthreads();
        #pragma unroll
        for (int t = 0; t < 16; t++) {
            int jj = jsub * 16 + t;
            int jg = c * 128 + jj;
            float p  = p_row[w * S_ + jg];
            int   rm = rm_row[w * S_ + jg];
            float4 vv = *(const float4*)&kvbuf[jj * 36 + d0];
            float4 rv = *(const float4*)&relbuf[rm * 36 + d0];
            acc.x += p * (vv.x + rv.x);
            acc.y += p * (vv.y + rv.y);
            acc.z += p * (vv.z + rv.z);
            acc.w += p * (vv.w + rv.w);
        }
    }

    #pragma unroll
    for (int off = 8; off < 64; off <<= 1) {
        acc.x += __shfl_xor(acc.x, off);
        acc.y += __shfl_xor(acc.y, off);
        acc.z += __shfl_xor(acc.z, off);
        acc.w += __shfl_xor(acc.w, off);
    }
    if (jsub == 0) {
        *(float4*)&CTX[(size_t)(b * S_ + q0 + w) * DH + h * PH + d0] = acc;
    }
}

// ---------------------------------------------------------------------------
extern "C" void kernel_launch(void* const* d_in, const int* in_sizes, int n_in,
                              void* d_out, int out_size, void* d_ws, size_t ws_size,
                              hipStream_t stream)
{
    const float* hidden = (const float*)d_in[0];
    const float* Wq = (const float*)d_in[1];  const float* bq = (const float*)d_in[2];
    const float* Wk = (const float*)d_in[3];  const float* bk = (const float*)d_in[4];
    const float* Wv = (const float*)d_in[5];  const float* bv = (const float*)d_in[6];
    const float* Wo = (const float*)d_in[7];  const float* bo = (const float*)d_in[8];
    const float* relk = (const float*)d_in[9];
    const float* relv = (const float*)d_in[10];
    const float* W1 = (const float*)d_in[11]; const float* b1 = (const float*)d_in[12];
    const float* W2 = (const float*)d_in[13]; const float* b2 = (const float*)d_in[14];
    const int*   RM = (const int*)d_in[15];
    float* out = (float*)d_out;

    const size_t SZ = (size_t)MROWS * DH;      // 3,276,800 elems

    char* ws = (char*)d_ws;
    float* qb  = (float*)(ws + 0);                    // 13,107,200 B (q -> ctx)
    float* kb  = (float*)(ws + 13107200);             // k
    float* vb  = (float*)(ws + 26214400);             // v
    unsigned short* hb   = (unsigned short*)(ws + 39321600);  // hidden bf16
    unsigned short* ctxb = (unsigned short*)(ws + 45875200);  // ctx bf16
    unsigned short* aob  = (unsigned short*)(ws + 52428800);  // attn_out bf16
    unsigned short* hbb  = (unsigned short*)(ws + 58982400);  // ffn-hidden bf16
    unsigned short* Wt   = (unsigned short*)(ws + 65536000);  // 6 x [1600][1600] bf16
    const size_t WSZ = (size_t)DH * DH;
    unsigned short *Wtq = Wt,           *Wtk = Wt + WSZ,     *Wtv = Wt + 2*WSZ,
                   *Wto = Wt + 3*WSZ,   *Wt1 = Wt + 4*WSZ,   *Wt2 = Wt + 5*WSZ;
    // total ws use: ~96.3 MB

    // casts
    fcast_k<<<dim3((SZ/4 + 255)/256), 256, 0, stream>>>(hidden, hb, (int)(SZ/4));
    wcast_k<<<dim3(DH/32, DH/32, 6), 256, 0, stream>>>(Wq, Wk, Wv, Wo, W1, W2, Wt);

    // QKV (fp32 out for attention)
    gemm_bf16_k<false, true, false><<<dim3(DH/BN, MROWS/BM, 3), 256, 0, stream>>>(
        hb, Wtq, Wtk, Wtv, bq, bk, bv, qb, kb, vb, nullptr, nullptr, nullptr);

    // attention: ctx -> qb (aliases q; each block writes only what it read)
    attn_k<<<dim3(S_/4, NH, B_), 256, 0, stream>>>(qb, kb, vb, relk, relv, RM, qb);

    fcast_k<<<dim3((SZ/4 + 255)/256), 256, 0, stream>>>(qb, ctxb, (int)(SZ/4));

    // attn_out = ctx @ Wo + bo  (bf16 out only)
    gemm_bf16_k<false, false, true><<<dim3(DH/BN, MROWS/BM, 1), 256, 0, stream>>>(
        ctxb, Wto, Wto, Wto, bo, bo, bo, nullptr, nullptr, nullptr, aob, aob, aob);

    // h = gelu(attn_out @ W1 + b1)  (bf16 out only)
    gemm_bf16_k<true, false, true><<<dim3(DH/BN, MROWS/BM, 1), 256, 0, stream>>>(
        aob, Wt1, Wt1, Wt1, b1, b1, b1, nullptr, nullptr, nullptr, hbb, hbb, hbb);

    // out = h @ W2 + b2  (fp32 out = d_out)
    gemm_bf16_k<false, true, false><<<dim3(DH/BN, MROWS/BM, 1), 256, 0, stream>>>(
        hbb, Wt2, Wt2, Wt2, b2, b2, b2, out, out, out, nullptr, nullptr, nullptr);
}

// Round 3
// 755.804 us; speedup vs baseline: 2.3165x; 1.3554x over previous
//
#include <hip/hip_runtime.h>
#include <math.h>

#define B_   4
#define S_   512
#define DH   1600
#define NH   50
#define PH   32
#define NREL 100
#define MROWS (B_ * S_)          // 2048

typedef _Float16 f16x8 __attribute__((ext_vector_type(8)));
typedef float  floatx4 __attribute__((ext_vector_type(4)));

__device__ __forceinline__ float gelu_f(float x) {
    return 0.5f * x * (1.0f + erff(x * 0.70710678118654752f));
}

__device__ __forceinline__ unsigned short f2h_u(float f) {
    _Float16 h = (_Float16)f;
    return __builtin_bit_cast(unsigned short, h);
}

// ---------------------------------------------------------------------------
// fcast: flat fp32 -> f16
// ---------------------------------------------------------------------------
__global__ __launch_bounds__(256)
void fcast_k(const float* __restrict__ in, unsigned short* __restrict__ out, int n4)
{
    int i = blockIdx.x * 256 + threadIdx.x;
    if (i < n4) {
        float4 v = *(const float4*)&in[i * 4];
        ushort4 o = { f2h_u(v.x), f2h_u(v.y), f2h_u(v.z), f2h_u(v.w) };
        *(ushort4*)&out[i * 4] = o;
    }
}

// ---------------------------------------------------------------------------
// wcast: W[K][N] fp32 -> Wt[N][K] f16, 6 weights via blockIdx.z.
// ---------------------------------------------------------------------------
__global__ __launch_bounds__(256)
void wcast_k(const float* __restrict__ W0, const float* __restrict__ W1,
             const float* __restrict__ W2, const float* __restrict__ W3,
             const float* __restrict__ W4, const float* __restrict__ W5,
             unsigned short* __restrict__ T)
{
    const int z = blockIdx.z;
    const float* W = (z==0)?W0:(z==1)?W1:(z==2)?W2:(z==3)?W3:(z==4)?W4:W5;
    unsigned short* out = T + (size_t)z * DH * DH;

    __shared__ float tile[32][33];
    const int t = threadIdx.x;
    const int n0 = blockIdx.x * 32, k0 = blockIdx.y * 32;
    const int r = t >> 3, c4 = (t & 7) * 4;

    float4 v = *(const float4*)&W[(size_t)(k0 + r) * DH + n0 + c4];
    tile[r][c4 + 0] = v.x; tile[r][c4 + 1] = v.y;
    tile[r][c4 + 2] = v.z; tile[r][c4 + 3] = v.w;
    __syncthreads();

    ushort4 o = { f2h_u(tile[c4 + 0][r]), f2h_u(tile[c4 + 1][r]),
                  f2h_u(tile[c4 + 2][r]), f2h_u(tile[c4 + 3][r]) };
    *(ushort4*)&out[(size_t)(n0 + r) * DH + k0 + c4] = o;
}

// ---------------------------------------------------------------------------
// f16 MFMA GEMM: C = A @ Wt^T + bias (Wt = [N][K] f16). Identical structure
// to the verified R2 bf16 kernel; only dtype changed (C/D layout is
// dtype-independent on gfx950).
// ---------------------------------------------------------------------------
#define BM 128
#define BN 64
#define BK 32
#define LDA 40

template<bool GELU, bool WF32, bool WF16>
__global__ __launch_bounds__(256)
void gemm_f16_k(const unsigned short* __restrict__ Ab,
                const unsigned short* __restrict__ Bt0,
                const unsigned short* __restrict__ Bt1,
                const unsigned short* __restrict__ Bt2,
                const float* __restrict__ bi0, const float* __restrict__ bi1,
                const float* __restrict__ bi2,
                float* __restrict__ Cf0, float* __restrict__ Cf1, float* __restrict__ Cf2,
                unsigned short* __restrict__ Ch0, unsigned short* __restrict__ Ch1,
                unsigned short* __restrict__ Ch2)
{
    const int z = blockIdx.z;
    const unsigned short* Bt = (z==0)?Bt0:(z==1)?Bt1:Bt2;
    const float* bi = (z==0)?bi0:(z==1)?bi1:bi2;
    float* Cf = (z==0)?Cf0:(z==1)?Cf1:Cf2;
    unsigned short* Ch = (z==0)?Ch0:(z==1)?Ch1:Ch2;

    __shared__ unsigned short As[BM * LDA];
    __shared__ unsigned short Bs[BN * LDA];

    const int tid = threadIdx.x;
    const int lane = tid & 63, w = tid >> 6;
    const int bm = blockIdx.y * BM, bn = blockIdx.x * BN;
    const int wm = (w >> 1) * 64, wn = (w & 1) * 32;

    const int ac0 = tid, ac1 = tid + 256;
    const size_t aoff0 = (size_t)(bm + (ac0 >> 2)) * DH + (ac0 & 3) * 8;
    const size_t aoff1 = (size_t)(bm + (ac1 >> 2)) * DH + (ac1 & 3) * 8;
    const size_t boff  = (size_t)(bn + (tid >> 2)) * DH + (tid & 3) * 8;
    const int al0 = (ac0 >> 2) * LDA + (ac0 & 3) * 8;
    const int al1 = (ac1 >> 2) * LDA + (ac1 & 3) * 8;
    const int bl  = (tid >> 2) * LDA + (tid & 3) * 8;

    const int fl_m = lane & 15, fl_g = (lane >> 4) * 8;

    floatx4 acc[4][2] = {};

    for (int k0 = 0; k0 < DH; k0 += BK) {
        uint4 av0 = *(const uint4*)&Ab[aoff0 + k0];
        uint4 av1 = *(const uint4*)&Ab[aoff1 + k0];
        uint4 bv  = *(const uint4*)&Bt[boff + k0];
        __syncthreads();
        *(uint4*)&As[al0] = av0;
        *(uint4*)&As[al1] = av1;
        *(uint4*)&Bs[bl]  = bv;
        __syncthreads();

        f16x8 af[4], bf[2];
        #pragma unroll
        for (int mt = 0; mt < 4; mt++)
            af[mt] = *(const f16x8*)&As[(wm + mt * 16 + fl_m) * LDA + fl_g];
        #pragma unroll
        for (int nt = 0; nt < 2; nt++)
            bf[nt] = *(const f16x8*)&Bs[(wn + nt * 16 + fl_m) * LDA + fl_g];

        #pragma unroll
        for (int mt = 0; mt < 4; mt++)
            #pragma unroll
            for (int nt = 0; nt < 2; nt++)
                acc[mt][nt] = __builtin_amdgcn_mfma_f32_16x16x32_f16(
                    af[mt], bf[nt], acc[mt][nt], 0, 0, 0);
    }

    const int row_q = (lane >> 4) * 4;
    #pragma unroll
    for (int mt = 0; mt < 4; mt++) {
        #pragma unroll
        for (int nt = 0; nt < 2; nt++) {
            const int col = bn + wn + nt * 16 + fl_m;
            const float bias = bi[col];
            #pragma unroll
            for (int r = 0; r < 4; r++) {
                const int row = bm + wm + mt * 16 + row_q + r;
                float v = acc[mt][nt][r] + bias;
                if (GELU) v = gelu_f(v);
                if (WF32) Cf[(size_t)row * DH + col] = v;
                if (WF16) Ch[(size_t)row * DH + col] = f2h_u(v);
            }
        }
    }
}

// ---------------------------------------------------------------------------
// MFMA relation-aware attention. Block = (b, h, 64-q tile), 256 thr = 4 waves
// (16 q rows each). All LDS frag access patterns bank-checked (stride-40/520
// rows -> uniform quad spread).
//   P0 stage q(fp32), rel_k, rm(u8), zero wsum | P1 qrel = q @ rel_k^T (VALU)
//   P2 stage K rows, rel_v | P3 scores MFMA + bias gather + softmax + wsum
//   scatter | P4 stage V^T | P5 PV MFMA (P via per-wave LDS roundtrip) +
//   ctx_rel = wsum @ rel_v (VALU) -> ctx f16
// ---------------------------------------------------------------------------
__global__ __launch_bounds__(256, 1)
void attn_k(const unsigned short* __restrict__ Qg,
            const unsigned short* __restrict__ Kg,
            const unsigned short* __restrict__ Vg,
            const float* __restrict__ relk, const float* __restrict__ relv,
            const int* __restrict__ RM, unsigned short* __restrict__ CTX)
{
    __shared__ union {
        unsigned short Kb[512 * 40];   // 40960 B  (score phase)
        unsigned short VT[32 * 520];   // 33280 B  (PV phase)
        float          qf[64 * 36];    // 36864 B  (qrel phase)
    } big;
    __shared__ unsigned char rmb[64 * 516];    // 33024 B
    __shared__ float qrel[64 * 101];           // 25856 B
    __shared__ float wsum[64 * 101];           // 25856 B
    __shared__ float relb[NREL * 36];          // 14400 B (rel_k then rel_v)
    __shared__ unsigned short Pb[4][2][16 * 40]; // 10240 B

    const int tid = threadIdx.x;
    const int w = tid >> 6, lane = tid & 63;
    const int cl = lane & 15, quad = lane >> 4;
    const int b = blockIdx.z, h = blockIdx.y, q0 = blockIdx.x * 64;
    const float scale = 0.17677669529663689f;   // 1/sqrt(32)

    // ---------------- P0 ----------------
    for (int i = tid; i < 64 * 101; i += 256) wsum[i] = 0.f;
    {   // q tile -> fp32 LDS [64][36]
        int row = tid >> 2, g = tid & 3;
        uint4 qv = *(const uint4*)&Qg[(size_t)(b * S_ + q0 + row) * DH + h * PH + g * 8];
        f16x8 qh = __builtin_bit_cast(f16x8, qv);
        #pragma unroll
        for (int j = 0; j < 8; j++) big.qf[row * 36 + g * 8 + j] = (float)qh[j];
    }
    for (int i = tid; i < NREL * 8; i += 256) {   // rel_k fp32 [100][36]
        int r = i >> 3, dg = i & 7;
        *(float4*)&relb[r * 36 + dg * 4] = *(const float4*)&relk[r * PH + dg * 4];
    }
    #pragma unroll
    for (int it = 0; it < 32; it++) {   // rm -> u8 [64][516]
        int idx = it * 256 + tid;
        int key4 = idx & 127, ql = idx >> 7;
        int4 rv = *(const int4*)&RM[(size_t)(b * S_ + q0 + ql) * S_ + key4 * 4];
        uchar4 o = { (unsigned char)rv.x, (unsigned char)rv.y,
                     (unsigned char)rv.z, (unsigned char)rv.w };
        *(uchar4*)&rmb[ql * 516 + key4 * 4] = o;
    }
    __syncthreads();

    // ---------------- P1: qrel[q][r] ----------------
    {
        const int q = tid >> 2, rsub = tid & 3;
        float qv[PH];
        #pragma unroll
        for (int d = 0; d < PH; d++) qv[d] = big.qf[q * 36 + d];
        for (int i = 0; i < 25; i++) {
            int r = rsub * 25 + i;
            float s = 0.f;
            #pragma unroll
            for (int d = 0; d < PH; d++) s += qv[d] * relb[r * 36 + d];
            qrel[q * 101 + r] = s;
        }
    }
    __syncthreads();

    // ---------------- P2: stage K rows + rel_v ----------------
    #pragma unroll
    for (int it = 0; it < 8; it++) {
        int idx = it * 256 + tid;
        int key = idx >> 2, g = idx & 3;
        uint4 kv = *(const uint4*)&Kg[(size_t)(b * S_ + key) * DH + h * PH + g * 8];
        *(uint4*)&big.Kb[key * 40 + g * 8] = kv;
    }
    for (int i = tid; i < NREL * 8; i += 256) {
        int r = i >> 3, dg = i & 7;
        *(float4*)&relb[r * 36 + dg * 4] = *(const float4*)&relv[r * PH + dg * 4];
    }
    __syncthreads();

    // ---------------- P3: scores + bias + softmax + scatter ----------------
    floatx4 acc[32];
    {
        f16x8 qa = __builtin_bit_cast(f16x8, *(const uint4*)
            &Qg[(size_t)(b * S_ + q0 + w * 16 + cl) * DH + h * PH + quad * 8]);
        #pragma unroll
        for (int t = 0; t < 32; t++) {
            f16x8 kf = *(const f16x8*)&big.Kb[(t * 16 + cl) * 40 + quad * 8];
            acc[t] = __builtin_amdgcn_mfma_f32_16x16x32_f16(qa, kf, (floatx4){}, 0, 0, 0);
        }
        // bias + scale (C layout: col=key=cl+16t, row=q= w*16+quad*4+r)
        #pragma unroll
        for (int t = 0; t < 32; t++) {
            #pragma unroll
            for (int r = 0; r < 4; r++) {
                int ql = w * 16 + quad * 4 + r;
                int rm = rmb[ql * 516 + t * 16 + cl];
                acc[t][r] = (acc[t][r] + qrel[ql * 101 + rm]) * scale;
            }
        }
        // softmax per row (4 rows in parallel, reduce over 32 regs + 16 lanes)
        float mx[4] = {-1e30f, -1e30f, -1e30f, -1e30f};
        #pragma unroll
        for (int t = 0; t < 32; t++)
            #pragma unroll
            for (int r = 0; r < 4; r++) mx[r] = fmaxf(mx[r], acc[t][r]);
        #pragma unroll
        for (int r = 0; r < 4; r++) {
            #pragma unroll
            for (int off = 1; off < 16; off <<= 1)
                mx[r] = fmaxf(mx[r], __shfl_xor(mx[r], off));
        }
        float sm[4] = {};
        #pragma unroll
        for (int t = 0; t < 32; t++)
            #pragma unroll
            for (int r = 0; r < 4; r++) {
                float e = __expf(acc[t][r] - mx[r]);
                acc[t][r] = e; sm[r] += e;
            }
        #pragma unroll
        for (int r = 0; r < 4; r++) {
            #pragma unroll
            for (int off = 1; off < 16; off <<= 1)
                sm[r] += __shfl_xor(sm[r], off);
            sm[r] = 1.0f / sm[r];
        }
        #pragma unroll
        for (int t = 0; t < 32; t++)
            #pragma unroll
            for (int r = 0; r < 4; r++) acc[t][r] *= sm[r];
        // wsum scatter
        #pragma unroll
        for (int t = 0; t < 32; t++) {
            #pragma unroll
            for (int r = 0; r < 4; r++) {
                int ql = w * 16 + quad * 4 + r;
                int rm = rmb[ql * 516 + t * 16 + cl];
                atomicAdd(&wsum[ql * 101 + rm], acc[t][r]);
            }
        }
    }
    __syncthreads();

    // ---------------- P4: stage V^T [32 d][520 keys] ----------------
    #pragma unroll
    for (int it = 0; it < 8; it++) {
        int idx = it * 256 + tid;
        int key = idx >> 2, part = idx & 3;
        uint4 vv = *(const uint4*)&Vg[(size_t)(b * S_ + key) * DH + h * PH + part * 8];
        f16x8 vh = __builtin_bit_cast(f16x8, vv);
        #pragma unroll
        for (int j = 0; j < 8; j++)
            big.VT[(part * 8 + j) * 520 + key] = f2h_u((float)vh[j]) , (void)0;
    }
    __syncthreads();

    // ---------------- P5: PV + ctx_rel + write ----------------
    {
        floatx4 ctx[2] = {};
        #pragma unroll
        for (int c = 0; c < 16; c++) {
            // write P chunk (32 keys) to per-wave buffer, C-layout -> rows
            #pragma unroll
            for (int tt = 0; tt < 2; tt++) {
                #pragma unroll
                for (int r = 0; r < 4; r++)
                    Pb[w][c & 1][(quad * 4 + r) * 40 + tt * 16 + cl] =
                        f2h_u(acc[c * 2 + tt][r]);
            }
            f16x8 pa = *(const f16x8*)&Pb[w][c & 1][cl * 40 + quad * 8];
            #pragma unroll
            for (int nt = 0; nt < 2; nt++) {
                f16x8 vf = *(const f16x8*)&big.VT[(nt * 16 + cl) * 520 + c * 32 + quad * 8];
                ctx[nt] = __builtin_amdgcn_mfma_f32_16x16x32_f16(pa, vf, ctx[nt], 0, 0, 0);
            }
        }
        // ctx_rel = wsum @ rel_v
        for (int r = 0; r < NREL; r++) {
            float rv0 = relb[r * 36 + cl];
            float rv1 = relb[r * 36 + 16 + cl];
            #pragma unroll
            for (int rr = 0; rr < 4; rr++) {
                float ws = wsum[(w * 16 + quad * 4 + rr) * 101 + r];
                ctx[0][rr] += ws * rv0;
                ctx[1][rr] += ws * rv1;
            }
        }
        #pragma unroll
        for (int nt = 0; nt < 2; nt++) {
            #pragma unroll
            for (int rr = 0; rr < 4; rr++) {
                int row = b * S_ + q0 + w * 16 + quad * 4 + rr;
                int col = h * PH + nt * 16 + cl;
                CTX[(size_t)row * DH + col] = f2h_u(ctx[nt][rr]);
            }
        }
    }
}

// ---------------------------------------------------------------------------
extern "C" void kernel_launch(void* const* d_in, const int* in_sizes, int n_in,
                              void* d_out, int out_size, void* d_ws, size_t ws_size,
                              hipStream_t stream)
{
    const float* hidden = (const float*)d_in[0];
    const float* Wq = (const float*)d_in[1];  const float* bq = (const float*)d_in[2];
    const float* Wk = (const float*)d_in[3];  const float* bk = (const float*)d_in[4];
    const float* Wv = (const float*)d_in[5];  const float* bv = (const float*)d_in[6];
    const float* Wo = (const float*)d_in[7];  const float* bo = (const float*)d_in[8];
    const float* relk = (const float*)d_in[9];
    const float* relv = (const float*)d_in[10];
    const float* W1 = (const float*)d_in[11]; const float* b1 = (const float*)d_in[12];
    const float* W2 = (const float*)d_in[13]; const float* b2 = (const float*)d_in[14];
    const int*   RM = (const int*)d_in[15];
    float* out = (float*)d_out;

    const size_t SZ = (size_t)MROWS * DH;          // 3,276,800 elems
    const size_t SZB = SZ * 2;                     // f16 bytes

    char* ws = (char*)d_ws;
    unsigned short* hb   = (unsigned short*)(ws);              // hidden f16
    unsigned short* qf   = (unsigned short*)(ws + SZB);        // q f16
    unsigned short* kf   = (unsigned short*)(ws + 2*SZB);      // k f16
    unsigned short* vf   = (unsigned short*)(ws + 3*SZB);      // v f16
    unsigned short* ctxf = (unsigned short*)(ws + 4*SZB);      // ctx f16
    unsigned short* aof  = (unsigned short*)(ws + 5*SZB);      // attn_out f16
    unsigned short* hff  = (unsigned short*)(ws + 6*SZB);      // ffn hidden f16
    unsigned short* Wt   = (unsigned short*)(ws + 7*SZB);      // 6 x [N][K] f16
    const size_t WSZ = (size_t)DH * DH;
    unsigned short *Wtq = Wt,         *Wtk = Wt + WSZ,   *Wtv = Wt + 2*WSZ,
                   *Wto = Wt + 3*WSZ, *Wt1 = Wt + 4*WSZ, *Wt2 = Wt + 5*WSZ;

    fcast_k<<<dim3((SZ/4 + 255)/256), 256, 0, stream>>>(hidden, hb, (int)(SZ/4));
    wcast_k<<<dim3(DH/32, DH/32, 6), 256, 0, stream>>>(Wq, Wk, Wv, Wo, W1, W2, Wt);

    // QKV (f16 out)
    gemm_f16_k<false, false, true><<<dim3(DH/BN, MROWS/BM, 3), 256, 0, stream>>>(
        hb, Wtq, Wtk, Wtv, bq, bk, bv,
        nullptr, nullptr, nullptr, qf, kf, vf);

    attn_k<<<dim3(S_/64, NH, B_), 256, 0, stream>>>(qf, kf, vf, relk, relv, RM, ctxf);

    // attn_out = ctx @ Wo + bo
    gemm_f16_k<false, false, true><<<dim3(DH/BN, MROWS/BM, 1), 256, 0, stream>>>(
        ctxf, Wto, Wto, Wto, bo, bo, bo,
        nullptr, nullptr, nullptr, aof, aof, aof);

    // h = gelu(attn_out @ W1 + b1)
    gemm_f16_k<true, false, true><<<dim3(DH/BN, MROWS/BM, 1), 256, 0, stream>>>(
        aof, Wt1, Wt1, Wt1, b1, b1, b1,
        nullptr, nullptr, nullptr, hff, hff, hff);

    // out = h @ W2 + b2  (fp32 out)
    gemm_f16_k<false, true, false><<<dim3(DH/BN, MROWS/BM, 1), 256, 0, stream>>>(
        hff, Wt2, Wt2, Wt2, b2, b2, b2,
        out, out, out, nullptr, nullptr, nullptr);
}

// Round 8
// 754.602 us; speedup vs baseline: 2.3202x; 1.0016x over previous
//
#include <hip/hip_runtime.h>
#include <math.h>

#define B_   4
#define S_   512
#define DH   1600
#define NH   50
#define PH   32
#define NREL 100
#define MROWS (B_ * S_)          // 2048

typedef _Float16 f16x8 __attribute__((ext_vector_type(8)));
typedef float  floatx4 __attribute__((ext_vector_type(4)));

__device__ __forceinline__ float gelu_f(float x) {
    return 0.5f * x * (1.0f + erff(x * 0.70710678118654752f));
}

__device__ __forceinline__ unsigned short f2h_u(float f) {
    _Float16 h = (_Float16)f;
    return __builtin_bit_cast(unsigned short, h);
}

// ---------------------------------------------------------------------------
// fcast: flat fp32 -> f16
// ---------------------------------------------------------------------------
__global__ __launch_bounds__(256)
void fcast_k(const float* __restrict__ in, unsigned short* __restrict__ out, int n4)
{
    int i = blockIdx.x * 256 + threadIdx.x;
    if (i < n4) {
        float4 v = *(const float4*)&in[i * 4];
        ushort4 o = { f2h_u(v.x), f2h_u(v.y), f2h_u(v.z), f2h_u(v.w) };
        *(ushort4*)&out[i * 4] = o;
    }
}

// ---------------------------------------------------------------------------
// wcast: W[K][N] fp32 -> Wt[N][K] f16, 6 weights via blockIdx.z.
// ---------------------------------------------------------------------------
__global__ __launch_bounds__(256)
void wcast_k(const float* __restrict__ W0, const float* __restrict__ W1,
             const float* __restrict__ W2, const float* __restrict__ W3,
             const float* __restrict__ W4, const float* __restrict__ W5,
             unsigned short* __restrict__ T)
{
    const int z = blockIdx.z;
    const float* W = (z==0)?W0:(z==1)?W1:(z==2)?W2:(z==3)?W3:(z==4)?W4:W5;
    unsigned short* out = T + (size_t)z * DH * DH;

    __shared__ float tile[32][33];
    const int t = threadIdx.x;
    const int n0 = blockIdx.x * 32, k0 = blockIdx.y * 32;
    const int r = t >> 3, c4 = (t & 7) * 4;

    float4 v = *(const float4*)&W[(size_t)(k0 + r) * DH + n0 + c4];
    tile[r][c4 + 0] = v.x; tile[r][c4 + 1] = v.y;
    tile[r][c4 + 2] = v.z; tile[r][c4 + 3] = v.w;
    __syncthreads();

    ushort4 o = { f2h_u(tile[c4 + 0][r]), f2h_u(tile[c4 + 1][r]),
                  f2h_u(tile[c4 + 2][r]), f2h_u(tile[c4 + 3][r]) };
    *(ushort4*)&out[(size_t)(n0 + r) * DH + k0 + c4] = o;
}

// ---------------------------------------------------------------------------
// f16 MFMA GEMM: C = A @ Wt^T + bias (Wt = [N][K] f16). Identical structure
// to the verified R2 bf16 kernel; only dtype changed (C/D layout is
// dtype-independent on gfx950).
// ---------------------------------------------------------------------------
#define BM 128
#define BN 64
#define BK 32
#define LDA 40

template<bool GELU, bool WF32, bool WF16>
__global__ __launch_bounds__(256)
void gemm_f16_k(const unsigned short* __restrict__ Ab,
                const unsigned short* __restrict__ Bt0,
                const unsigned short* __restrict__ Bt1,
                const unsigned short* __restrict__ Bt2,
                const float* __restrict__ bi0, const float* __restrict__ bi1,
                const float* __restrict__ bi2,
                float* __restrict__ Cf0, float* __restrict__ Cf1, float* __restrict__ Cf2,
                unsigned short* __restrict__ Ch0, unsigned short* __restrict__ Ch1,
                unsigned short* __restrict__ Ch2)
{
    const int z = blockIdx.z;
    const unsigned short* Bt = (z==0)?Bt0:(z==1)?Bt1:Bt2;
    const float* bi = (z==0)?bi0:(z==1)?bi1:bi2;
    float* Cf = (z==0)?Cf0:(z==1)?Cf1:Cf2;
    unsigned short* Ch = (z==0)?Ch0:(z==1)?Ch1:Ch2;

    __shared__ unsigned short As[BM * LDA];
    __shared__ unsigned short Bs[BN * LDA];

    const int tid = threadIdx.x;
    const int lane = tid & 63, w = tid >> 6;
    const int bm = blockIdx.y * BM, bn = blockIdx.x * BN;
    const int wm = (w >> 1) * 64, wn = (w & 1) * 32;

    const int ac0 = tid, ac1 = tid + 256;
    const size_t aoff0 = (size_t)(bm + (ac0 >> 2)) * DH + (ac0 & 3) * 8;
    const size_t aoff1 = (size_t)(bm + (ac1 >> 2)) * DH + (ac1 & 3) * 8;
    const size_t boff  = (size_t)(bn + (tid >> 2)) * DH + (tid & 3) * 8;
    const int al0 = (ac0 >> 2) * LDA + (ac0 & 3) * 8;
    const int al1 = (ac1 >> 2) * LDA + (ac1 & 3) * 8;
    const int bl  = (tid >> 2) * LDA + (tid & 3) * 8;

    const int fl_m = lane & 15, fl_g = (lane >> 4) * 8;

    floatx4 acc[4][2] = {};

    for (int k0 = 0; k0 < DH; k0 += BK) {
        uint4 av0 = *(const uint4*)&Ab[aoff0 + k0];
        uint4 av1 = *(const uint4*)&Ab[aoff1 + k0];
        uint4 bv  = *(const uint4*)&Bt[boff + k0];
        __syncthreads();
        *(uint4*)&As[al0] = av0;
        *(uint4*)&As[al1] = av1;
        *(uint4*)&Bs[bl]  = bv;
        __syncthreads();

        f16x8 af[4], bf[2];
        #pragma unroll
        for (int mt = 0; mt < 4; mt++)
            af[mt] = *(const f16x8*)&As[(wm + mt * 16 + fl_m) * LDA + fl_g];
        #pragma unroll
        for (int nt = 0; nt < 2; nt++)
            bf[nt] = *(const f16x8*)&Bs[(wn + nt * 16 + fl_m) * LDA + fl_g];

        #pragma unroll
        for (int mt = 0; mt < 4; mt++)
            #pragma unroll
            for (int nt = 0; nt < 2; nt++)
                acc[mt][nt] = __builtin_amdgcn_mfma_f32_16x16x32_f16(
                    af[mt], bf[nt], acc[mt][nt], 0, 0, 0);
    }

    const int row_q = (lane >> 4) * 4;
    #pragma unroll
    for (int mt = 0; mt < 4; mt++) {
        #pragma unroll
        for (int nt = 0; nt < 2; nt++) {
            const int col = bn + wn + nt * 16 + fl_m;
            const float bias = bi[col];
            #pragma unroll
            for (int r = 0; r < 4; r++) {
                const int row = bm + wm + mt * 16 + row_q + r;
                float v = acc[mt][nt][r] + bias;
                if (GELU) v = gelu_f(v);
                if (WF32) Cf[(size_t)row * DH + col] = v;
                if (WF16) Ch[(size_t)row * DH + col] = f2h_u(v);
            }
        }
    }
}

// ---------------------------------------------------------------------------
// MFMA relation-aware attention. Block = (b, h, 64-q tile), 256 thr = 4 waves
// (16 q rows each). All LDS frag access patterns bank-checked (stride-40/520
// rows -> uniform quad spread).
//   P0 stage q(fp32), rel_k, rm(u8), zero wsum | P1 qrel = q @ rel_k^T (VALU)
//   P2 stage K rows, rel_v | P3 scores MFMA + bias gather + softmax + wsum
//   scatter | P4 stage V^T | P5 PV MFMA (P via per-wave LDS roundtrip) +
//   ctx_rel = wsum @ rel_v (VALU) -> ctx f16
// ---------------------------------------------------------------------------
__global__ __launch_bounds__(256, 1)
void attn_k(const unsigned short* __restrict__ Qg,
            const unsigned short* __restrict__ Kg,
            const unsigned short* __restrict__ Vg,
            const float* __restrict__ relk, const float* __restrict__ relv,
            const int* __restrict__ RM, unsigned short* __restrict__ CTX)
{
    __shared__ union {
        unsigned short Kb[512 * 40];   // 40960 B  (score phase)
        unsigned short VT[32 * 520];   // 33280 B  (PV phase)
        float          qf[64 * 36];    // 36864 B  (qrel phase)
    } big;
    __shared__ unsigned char rmb[64 * 516];    // 33024 B
    __shared__ float qrel[64 * 101];           // 25856 B
    __shared__ float wsum[64 * 101];           // 25856 B
    __shared__ float relb[NREL * 36];          // 14400 B (rel_k then rel_v)
    __shared__ unsigned short Pb[4][2][16 * 40]; // 10240 B

    const int tid = threadIdx.x;
    const int w = tid >> 6, lane = tid & 63;
    const int cl = lane & 15, quad = lane >> 4;
    const int b = blockIdx.z, h = blockIdx.y, q0 = blockIdx.x * 64;
    const float scale = 0.17677669529663689f;   // 1/sqrt(32)

    // ---------------- P0 ----------------
    for (int i = tid; i < 64 * 101; i += 256) wsum[i] = 0.f;
    {   // q tile -> fp32 LDS [64][36]
        int row = tid >> 2, g = tid & 3;
        uint4 qv = *(const uint4*)&Qg[(size_t)(b * S_ + q0 + row) * DH + h * PH + g * 8];
        f16x8 qh = __builtin_bit_cast(f16x8, qv);
        #pragma unroll
        for (int j = 0; j < 8; j++) big.qf[row * 36 + g * 8 + j] = (float)qh[j];
    }
    for (int i = tid; i < NREL * 8; i += 256) {   // rel_k fp32 [100][36]
        int r = i >> 3, dg = i & 7;
        *(float4*)&relb[r * 36 + dg * 4] = *(const float4*)&relk[r * PH + dg * 4];
    }
    #pragma unroll
    for (int it = 0; it < 32; it++) {   // rm -> u8 [64][516]
        int idx = it * 256 + tid;
        int key4 = idx & 127, ql = idx >> 7;
        int4 rv = *(const int4*)&RM[(size_t)(b * S_ + q0 + ql) * S_ + key4 * 4];
        uchar4 o = { (unsigned char)rv.x, (unsigned char)rv.y,
                     (unsigned char)rv.z, (unsigned char)rv.w };
        *(uchar4*)&rmb[ql * 516 + key4 * 4] = o;
    }
    __syncthreads();

    // ---------------- P1: qrel[q][r] ----------------
    {
        const int q = tid >> 2, rsub = tid & 3;
        float qv[PH];
        #pragma unroll
        for (int d = 0; d < PH; d++) qv[d] = big.qf[q * 36 + d];
        for (int i = 0; i < 25; i++) {
            int r = rsub * 25 + i;
            float s = 0.f;
            #pragma unroll
            for (int d = 0; d < PH; d++) s += qv[d] * relb[r * 36 + d];
            qrel[q * 101 + r] = s;
        }
    }
    __syncthreads();

    // ---------------- P2: stage K rows + rel_v ----------------
    #pragma unroll
    for (int it = 0; it < 8; it++) {
        int idx = it * 256 + tid;
        int key = idx >> 2, g = idx & 3;
        uint4 kv = *(const uint4*)&Kg[(size_t)(b * S_ + key) * DH + h * PH + g * 8];
        *(uint4*)&big.Kb[key * 40 + g * 8] = kv;
    }
    for (int i = tid; i < NREL * 8; i += 256) {
        int r = i >> 3, dg = i & 7;
        *(float4*)&relb[r * 36 + dg * 4] = *(const float4*)&relv[r * PH + dg * 4];
    }
    __syncthreads();

    // ---------------- P3: scores + bias + softmax + scatter ----------------
    floatx4 acc[32];
    {
        f16x8 qa = __builtin_bit_cast(f16x8, *(const uint4*)
            &Qg[(size_t)(b * S_ + q0 + w * 16 + cl) * DH + h * PH + quad * 8]);
        #pragma unroll
        for (int t = 0; t < 32; t++) {
            f16x8 kf = *(const f16x8*)&big.Kb[(t * 16 + cl) * 40 + quad * 8];
            acc[t] = __builtin_amdgcn_mfma_f32_16x16x32_f16(qa, kf, (floatx4){}, 0, 0, 0);
        }
        // bias + scale (C layout: col=key=cl+16t, row=q= w*16+quad*4+r)
        #pragma unroll
        for (int t = 0; t < 32; t++) {
            #pragma unroll
            for (int r = 0; r < 4; r++) {
                int ql = w * 16 + quad * 4 + r;
                int rm = rmb[ql * 516 + t * 16 + cl];
                acc[t][r] = (acc[t][r] + qrel[ql * 101 + rm]) * scale;
            }
        }
        // softmax per row (4 rows in parallel, reduce over 32 regs + 16 lanes)
        float mx[4] = {-1e30f, -1e30f, -1e30f, -1e30f};
        #pragma unroll
        for (int t = 0; t < 32; t++)
            #pragma unroll
            for (int r = 0; r < 4; r++) mx[r] = fmaxf(mx[r], acc[t][r]);
        #pragma unroll
        for (int r = 0; r < 4; r++) {
            #pragma unroll
            for (int off = 1; off < 16; off <<= 1)
                mx[r] = fmaxf(mx[r], __shfl_xor(mx[r], off));
        }
        float sm[4] = {};
        #pragma unroll
        for (int t = 0; t < 32; t++)
            #pragma unroll
            for (int r = 0; r < 4; r++) {
                float e = __expf(acc[t][r] - mx[r]);
                acc[t][r] = e; sm[r] += e;
            }
        #pragma unroll
        for (int r = 0; r < 4; r++) {
            #pragma unroll
            for (int off = 1; off < 16; off <<= 1)
                sm[r] += __shfl_xor(sm[r], off);
            sm[r] = 1.0f / sm[r];
        }
        #pragma unroll
        for (int t = 0; t < 32; t++)
            #pragma unroll
            for (int r = 0; r < 4; r++) acc[t][r] *= sm[r];
        // wsum scatter
        #pragma unroll
        for (int t = 0; t < 32; t++) {
            #pragma unroll
            for (int r = 0; r < 4; r++) {
                int ql = w * 16 + quad * 4 + r;
                int rm = rmb[ql * 516 + t * 16 + cl];
                atomicAdd(&wsum[ql * 101 + rm], acc[t][r]);
            }
        }
    }
    __syncthreads();

    // ---------------- P4: stage V^T [32 d][520 keys] ----------------
    #pragma unroll
    for (int it = 0; it < 8; it++) {
        int idx = it * 256 + tid;
        int key = idx >> 2, part = idx & 3;
        uint4 vv = *(const uint4*)&Vg[(size_t)(b * S_ + key) * DH + h * PH + part * 8];
        f16x8 vh = __builtin_bit_cast(f16x8, vv);
        #pragma unroll
        for (int j = 0; j < 8; j++)
            big.VT[(part * 8 + j) * 520 + key] = f2h_u((float)vh[j]) , (void)0;
    }
    __syncthreads();

    // ---------------- P5: PV + ctx_rel + write ----------------
    {
        floatx4 ctx[2] = {};
        #pragma unroll
        for (int c = 0; c < 16; c++) {
            // write P chunk (32 keys) to per-wave buffer, C-layout -> rows
            #pragma unroll
            for (int tt = 0; tt < 2; tt++) {
                #pragma unroll
                for (int r = 0; r < 4; r++)
                    Pb[w][c & 1][(quad * 4 + r) * 40 + tt * 16 + cl] =
                        f2h_u(acc[c * 2 + tt][r]);
            }
            f16x8 pa = *(const f16x8*)&Pb[w][c & 1][cl * 40 + quad * 8];
            #pragma unroll
            for (int nt = 0; nt < 2; nt++) {
                f16x8 vf = *(const f16x8*)&big.VT[(nt * 16 + cl) * 520 + c * 32 + quad * 8];
                ctx[nt] = __builtin_amdgcn_mfma_f32_16x16x32_f16(pa, vf, ctx[nt], 0, 0, 0);
            }
        }
        // ctx_rel = wsum @ rel_v
        for (int r = 0; r < NREL; r++) {
            float rv0 = relb[r * 36 + cl];
            float rv1 = relb[r * 36 + 16 + cl];
            #pragma unroll
            for (int rr = 0; rr < 4; rr++) {
                float ws = wsum[(w * 16 + quad * 4 + rr) * 101 + r];
                ctx[0][rr] += ws * rv0;
                ctx[1][rr] += ws * rv1;
            }
        }
        #pragma unroll
        for (int nt = 0; nt < 2; nt++) {
            #pragma unroll
            for (int rr = 0; rr < 4; rr++) {
                int row = b * S_ + q0 + w * 16 + quad * 4 + rr;
                int col = h * PH + nt * 16 + cl;
                CTX[(size_t)row * DH + col] = f2h_u(ctx[nt][rr]);
            }
        }
    }
}

// ---------------------------------------------------------------------------
extern "C" void kernel_launch(void* const* d_in, const int* in_sizes, int n_in,
                              void* d_out, int out_size, void* d_ws, size_t ws_size,
                              hipStream_t stream)
{
    const float* hidden = (const float*)d_in[0];
    const float* Wq = (const float*)d_in[1];  const float* bq = (const float*)d_in[2];
    const float* Wk = (const float*)d_in[3];  const float* bk = (const float*)d_in[4];
    const float* Wv = (const float*)d_in[5];  const float* bv = (const float*)d_in[6];
    const float* Wo = (const float*)d_in[7];  const float* bo = (const float*)d_in[8];
    const float* relk = (const float*)d_in[9];
    const float* relv = (const float*)d_in[10];
    const float* W1 = (const float*)d_in[11]; const float* b1 = (const float*)d_in[12];
    const float* W2 = (const float*)d_in[13]; const float* b2 = (const float*)d_in[14];
    const int*   RM = (const int*)d_in[15];
    float* out = (float*)d_out;

    const size_t SZ = (size_t)MROWS * DH;          // 3,276,800 elems
    const size_t SZB = SZ * 2;                     // f16 bytes

    char* ws = (char*)d_ws;
    unsigned short* hb   = (unsigned short*)(ws);              // hidden f16
    unsigned short* qf   = (unsigned short*)(ws + SZB);        // q f16
    unsigned short* kf   = (unsigned short*)(ws + 2*SZB);      // k f16
    unsigned short* vf   = (unsigned short*)(ws + 3*SZB);      // v f16
    unsigned short* ctxf = (unsigned short*)(ws + 4*SZB);      // ctx f16
    unsigned short* aof  = (unsigned short*)(ws + 5*SZB);      // attn_out f16
    unsigned short* hff  = (unsigned short*)(ws + 6*SZB);      // ffn hidden f16
    unsigned short* Wt   = (unsigned short*)(ws + 7*SZB);      // 6 x [N][K] f16
    const size_t WSZ = (size_t)DH * DH;
    unsigned short *Wtq = Wt,         *Wtk = Wt + WSZ,   *Wtv = Wt + 2*WSZ,
                   *Wto = Wt + 3*WSZ, *Wt1 = Wt + 4*WSZ, *Wt2 = Wt + 5*WSZ;

    fcast_k<<<dim3((SZ/4 + 255)/256), 256, 0, stream>>>(hidden, hb, (int)(SZ/4));
    wcast_k<<<dim3(DH/32, DH/32, 6), 256, 0, stream>>>(Wq, Wk, Wv, Wo, W1, W2, Wt);

    // QKV (f16 out)
    gemm_f16_k<false, false, true><<<dim3(DH/BN, MROWS/BM, 3), 256, 0, stream>>>(
        hb, Wtq, Wtk, Wtv, bq, bk, bv,
        nullptr, nullptr, nullptr, qf, kf, vf);

    attn_k<<<dim3(S_/64, NH, B_), 256, 0, stream>>>(qf, kf, vf, relk, relv, RM, ctxf);

    // attn_out = ctx @ Wo + bo
    gemm_f16_k<false, false, true><<<dim3(DH/BN, MROWS/BM, 1), 256, 0, stream>>>(
        ctxf, Wto, Wto, Wto, bo, bo, bo,
        nullptr, nullptr, nullptr, aof, aof, aof);

    // h = gelu(attn_out @ W1 + b1)
    gemm_f16_k<true, false, true><<<dim3(DH/BN, MROWS/BM, 1), 256, 0, stream>>>(
        aof, Wt1, Wt1, Wt1, b1, b1, b1,
        nullptr, nullptr, nullptr, hff, hff, hff);

    // out = h @ W2 + b2  (fp32 out)
    gemm_f16_k<false, true, false><<<dim3(DH/BN, MROWS/BM, 1), 256, 0, stream>>>(
        hff, Wt2, Wt2, Wt2, b2, b2, b2,
        out, out, out, nullptr, nullptr, nullptr);
}